// Round 8
// baseline (123.310 us; speedup 1.0000x reference)
//
#include <hip/hip_runtime.h>
#include <hip/hip_fp16.h>

#define NNODES 50000
#define NREL   1000
#define NEDGES 1600000
#define FOUT   64
#define NEG_SLOPE 0.2f

#define SPAN   32                  // dst nodes per bucket (ln fits in 5 bits)
#define NBUCK  1563                // ceil(50000/32)
#define CAP    1280                // records per bucket (mean 1024, sigma 32 -> +8 sigma)
#define CHUNK  2048                // edges per distribute block
#define EPT    8                   // edges per thread
#define DBLK   782                 // ceil(NEDGES/CHUNK)
#define PREB   3188                // ceil((NNODES+NREL)*16/256) score blocks

// record layout: (ln<<26) | (sn<<10) | rn   -- ln<32, sn<65536, rn<1024

// -------- ws layout (bytes, 1 KiB aligned) --------
#define ALIGN1K(x) (((x) + 1023) & ~((size_t)1023))
static const size_t OFF_HS    = 0;                                            // float2[NNODES]
static const size_t OFF_RR    = ALIGN1K(OFF_HS    + sizeof(float2) * NNODES); // float2[NREL]
static const size_t OFF_CNT   = ALIGN1K(OFF_RR    + sizeof(float2) * NREL);   // int[NBUCK]
static const size_t OFF_H16   = ALIGN1K(OFF_CNT   + sizeof(int) * NBUCK);     // ushort[NNODES*64]
static const size_t OFF_R16   = ALIGN1K(OFF_H16   + sizeof(unsigned short) * NNODES * FOUT);
static const size_t OFF_STAGE = ALIGN1K(OFF_R16   + sizeof(unsigned short) * NREL * FOUT);
// stage: int[NBUCK*CAP] = 8.0 MB

// Fused: blocks [0, DBLK) bucket edges by dst>>5 (chunk reservation on zeroed
// counters); blocks [DBLK, ...) compute separable score tables AND the fp16
// copies of h / inputr used by the aggregate gathers.
__global__ __launch_bounds__(256) void prep_kernel(
    const float* __restrict__ h, const float* __restrict__ inputr,
    const float* __restrict__ w, const float* __restrict__ a_att,
    const int* __restrict__ A, int* __restrict__ ccnt, int* __restrict__ stage,
    float2* __restrict__ hs2, float2* __restrict__ rr2,
    unsigned short* __restrict__ h16, unsigned short* __restrict__ r16)
{
    const int t = threadIdx.x;
    if (blockIdx.x < DBLK) {
        __shared__ int lcnt[NBUCK];
        __shared__ int gbase[NBUCK];
        for (int i = t; i < NBUCK; i += 256) lcnt[i] = 0;
        __syncthreads();

        const int base = blockIdx.x * CHUNK;
        int rec[EPT];
        int bkt[EPT];
        int off[EPT];

        #pragma unroll
        for (int k = 0; k < EPT; k++) {
            const int e = base + k * 256 + t;
            if (e < NEDGES) {
                const int dn = __builtin_nontemporal_load(A + e);
                const int rn = __builtin_nontemporal_load(A + NEDGES + e);
                const int sn = __builtin_nontemporal_load(A + 2 * NEDGES + e);
                const int b  = dn >> 5;
                rec[k] = ((dn & 31) << 26) | (sn << 10) | rn;
                bkt[k] = b;
                off[k] = atomicAdd(&lcnt[b], 1);
            } else {
                off[k] = -1;
            }
        }
        __syncthreads();

        for (int i = t; i < NBUCK; i += 256) {
            const int c = lcnt[i];
            if (c > 0) gbase[i] = i * CAP + atomicAdd(&ccnt[i], c);
        }
        __syncthreads();

        #pragma unroll
        for (int k = 0; k < EPT; k++) {
            if (off[k] >= 0) {
                const int pos = gbase[bkt[k]] + off[k];
                if (pos < (bkt[k] + 1) * CAP)   // safety clamp (cannot trigger)
                    stage[pos] = rec[k];
            }
        }
        return;
    }

    // ---- score tables + fp16 staging ----
    const int lane = t & 15;
    const int f0   = lane << 2;
    const int g    = (blockIdx.x - DBLK) * 16 + (t >> 4);
    if (g >= NNODES + NREL) return;

    const float4 a00 = *(const float4*)(a_att +   0 + f0);
    const float4 a01 = *(const float4*)(a_att +  64 + f0);
    const float4 a10 = *(const float4*)(a_att + 128 + f0);
    const float4 a11 = *(const float4*)(a_att + 192 + f0);
    const float4 wv  = *(const float4*)(w + f0);

    float p0, p1;
    float4 v;
    if (g < NNODES) {
        v = *(const float4*)(h + (size_t)g * FOUT + f0);
        p0 = v.x * a00.x + v.y * a00.y + v.z * a00.z + v.w * a00.w;
        p1 = v.x * wv.x * a10.x + v.y * wv.y * a10.y
           + v.z * wv.z * a10.z + v.w * wv.w * a10.w;
    } else {
        v = *(const float4*)(inputr + (size_t)(g - NNODES) * FOUT + f0);
        p0 = v.x * a01.x + v.y * a01.y + v.z * a01.z + v.w * a01.w;
        p1 = v.x * a11.x + v.y * a11.y + v.z * a11.z + v.w * a11.w;
    }

    // fp16 staging copy (8 B/lane, coalesced 128 B per row)
    {
        ushort4 pk;
        pk.x = __half_as_ushort(__float2half(v.x));
        pk.y = __half_as_ushort(__float2half(v.y));
        pk.z = __half_as_ushort(__float2half(v.z));
        pk.w = __half_as_ushort(__float2half(v.w));
        if (g < NNODES) *(ushort4*)(h16 + (size_t)g * FOUT + f0) = pk;
        else            *(ushort4*)(r16 + (size_t)(g - NNODES) * FOUT + f0) = pk;
    }

    #pragma unroll
    for (int off = 8; off >= 1; off >>= 1) {
        p0 += __shfl_xor(p0, off, 16);
        p1 += __shfl_xor(p1, off, 16);
    }
    if (lane == 0) {
        if (g < NNODES) hs2[g] = make_float2(p0, p1);
        else            rr2[g - NNODES] = make_float2(p0, p1);
    }
}

// One block per bucket: load records to LDS, histogram 32 local nodes,
// shuffle scan, LDS counting sort; then 4 waves aggregate 8 nodes each
// (quarter-wave per edge, fp16 row gathers, register accumulation).
__global__ __launch_bounds__(256) void sortagg_kernel(
    const unsigned short* __restrict__ h16, const unsigned short* __restrict__ r16,
    const float* __restrict__ w,
    const int* __restrict__ stage, const int* __restrict__ ccnt,
    const float2* __restrict__ hs2, const float2* __restrict__ rr2,
    float* __restrict__ out)
{
    __shared__ int lrec[CAP];
    __shared__ int lsort[CAP];
    __shared__ int hist[SPAN];
    __shared__ int offs[SPAN];
    __shared__ int sstart[SPAN + 1];

    const int b = blockIdx.x;
    const int t = threadIdx.x;
    int cnt = ccnt[b];
    if (cnt > CAP) cnt = CAP;
    const int base = b * CAP;

    if (t < SPAN) hist[t] = 0;
    __syncthreads();

    for (int i = t; i < cnt; i += 256) {
        const int r = stage[base + i];
        lrec[i] = r;
        atomicAdd(&hist[((unsigned)r) >> 26], 1);
    }
    __syncthreads();

    if (t < SPAN) {   // lanes 0..31 of wave 0: inclusive shuffle scan
        const int c = hist[t];
        int v = c;
        #pragma unroll
        for (int d = 1; d < SPAN; d <<= 1) {
            const int u = __shfl_up(v, d);
            if (t >= d) v += u;
        }
        sstart[t] = v - c;
        offs[t]   = v - c;
        if (t == SPAN - 1) sstart[SPAN] = v;
    }
    __syncthreads();

    for (int i = t; i < cnt; i += 256) {
        const int r = lrec[i];
        const int p = atomicAdd(&offs[((unsigned)r) >> 26], 1);
        lsort[p] = r;
    }
    __syncthreads();

    // ---- aggregation: wave wv handles local nodes wv, wv+4, ..., wv+28 ----
    const int wv = t >> 6;
    const int q  = (t & 63) >> 4;      // quarter: which edge of a group of 4
    const int f4 = (t & 15) << 2;      // feature base (float4)
    const float4 wl = *(const float4*)(w + f4);

    for (int nl = wv; nl < SPAN; nl += 4) {
        const int node = b * SPAN + nl;
        if (node >= NNODES) break;     // only the last bucket; wave-uniform
        const int s0 = sstart[nl];
        const int s1 = sstart[nl + 1];

        float4 acc0 = make_float4(0.f, 0.f, 0.f, 0.f);
        float4 acc1 = make_float4(0.f, 0.f, 0.f, 0.f);
        float sum0 = 0.f, sum1 = 0.f;

        for (int i = s0 + q; i < s1; i += 4) {
            const int p  = lsort[i];               // LDS broadcast
            const int sn = (p >> 10) & 0xFFFF;
            const int rn = p & 1023;

            const float2 hv = hs2[sn];
            const float2 rv = rr2[rn];
            const float sc0 = hv.x + rv.x;
            const float sc1 = hv.y + rv.y;
            const float e0 = __expf(-fmaxf(sc0, NEG_SLOPE * sc0));
            const float e1 = __expf(-fmaxf(sc1, NEG_SLOPE * sc1));

            const uint2 su = *(const uint2*)(h16 + ((size_t)sn << 6) + f4);
            const uint2 ru = *(const uint2*)(r16 + ((size_t)rn << 6) + f4);
            const float2 sxy = __half22float2(__builtin_bit_cast(__half2, su.x));
            const float2 szw = __half22float2(__builtin_bit_cast(__half2, su.y));
            const float2 rxy = __half22float2(__builtin_bit_cast(__half2, ru.x));
            const float2 rzw = __half22float2(__builtin_bit_cast(__half2, ru.y));

            acc0.x += (sxy.x - rxy.x) * e0;
            acc0.y += (sxy.y - rxy.y) * e0;
            acc0.z += (szw.x - rzw.x) * e0;
            acc0.w += (szw.y - rzw.y) * e0;
            acc1.x += fmaf(sxy.x, wl.x, -rxy.x) * e1;
            acc1.y += fmaf(sxy.y, wl.y, -rxy.y) * e1;
            acc1.z += fmaf(szw.x, wl.z, -rzw.x) * e1;
            acc1.w += fmaf(szw.y, wl.w, -rzw.y) * e1;
            sum0 += e0;
            sum1 += e1;
        }

        // Combine the 4 quarters: xor-16 then xor-32 swap-adds.
        #pragma unroll
        for (int off = 16; off <= 32; off <<= 1) {
            acc0.x += __shfl_xor(acc0.x, off);
            acc0.y += __shfl_xor(acc0.y, off);
            acc0.z += __shfl_xor(acc0.z, off);
            acc0.w += __shfl_xor(acc0.w, off);
            acc1.x += __shfl_xor(acc1.x, off);
            acc1.y += __shfl_xor(acc1.y, off);
            acc1.z += __shfl_xor(acc1.z, off);
            acc1.w += __shfl_xor(acc1.w, off);
            sum0   += __shfl_xor(sum0, off);
            sum1   += __shfl_xor(sum1, off);
        }

        if (q == 0) {
            const float inv = 1.0f / sum0;
            float4 o = make_float4(acc0.x * inv, acc0.y * inv, acc0.z * inv, acc0.w * inv);
            *(float4*)(out + (size_t)node * FOUT + f4) = o;
        } else if (q == 1) {
            const float inv = 1.0f / sum1;
            float4 o = make_float4(acc1.x * inv, acc1.y * inv, acc1.z * inv, acc1.w * inv);
            *(float4*)(out + ((size_t)NNODES + node) * FOUT + f4) = o;
        }
    }
}

extern "C" void kernel_launch(void* const* d_in, const int* in_sizes, int n_in,
                              void* d_out, int out_size, void* d_ws, size_t ws_size,
                              hipStream_t stream) {
    const float* h      = (const float*)d_in[0];
    const float* inputr = (const float*)d_in[1];
    const int*   A      = (const int*)d_in[2];
    const float* w      = (const float*)d_in[3];
    const float* a_att  = (const float*)d_in[4];

    char* ws = (char*)d_ws;
    float2*         hs2   = (float2*)(ws + OFF_HS);
    float2*         rr2   = (float2*)(ws + OFF_RR);
    int*            ccnt  = (int*)(ws + OFF_CNT);
    unsigned short* h16   = (unsigned short*)(ws + OFF_H16);
    unsigned short* r16   = (unsigned short*)(ws + OFF_R16);
    int*            stage = (int*)(ws + OFF_STAGE);
    float*          out   = (float*)d_out;

    hipMemsetAsync(ccnt, 0, sizeof(int) * NBUCK, stream);

    // 1. Fused: edge bucketing + score tables + fp16 staging of h / inputr.
    prep_kernel<<<dim3(DBLK + PREB), dim3(256), 0, stream>>>(
        h, inputr, w, a_att, A, ccnt, stage, hs2, rr2, h16, r16);
    // 2. Fused per-bucket LDS counting sort + aggregation.
    sortagg_kernel<<<dim3(NBUCK), dim3(256), 0, stream>>>(
        h16, r16, w, stage, ccnt, hs2, rr2, out);
}

// Round 9
// 91.377 us; speedup vs baseline: 1.3495x; 1.3495x over previous
//
#include <hip/hip_runtime.h>
#include <hip/hip_fp16.h>

#define NNODES 50000
#define NREL   1000
#define NEDGES 1600000
#define FOUT   64
#define NEG_SLOPE 0.2f

#define SPAN   32                  // dst nodes per bucket (ln fits in 5 bits)
#define NBUCK  1563                // ceil(50000/32)
#define CAP    1280                // records per bucket (mean 1024, sigma 32 -> +8 sigma)
#define PTHR   1024                // prep block size
#define EPT    16                  // edges per thread in distribute
#define CHUNK  (PTHR * EPT)        // 16384 edges per distribute block
#define DBLK   98                  // ceil(NEDGES/CHUNK)
#define PREB   797                 // ceil((NNODES+NREL)/64) score blocks (64 rows/block)

// record layout: (ln<<26) | (sn<<10) | rn   -- ln<32, sn<65536, rn<1024

// -------- ws layout (bytes, 1 KiB aligned) --------
#define ALIGN1K(x) (((x) + 1023) & ~((size_t)1023))
static const size_t OFF_HS    = 0;                                            // float2[NNODES]
static const size_t OFF_RR    = ALIGN1K(OFF_HS    + sizeof(float2) * NNODES); // float2[NREL]
static const size_t OFF_CNT   = ALIGN1K(OFF_RR    + sizeof(float2) * NREL);   // int[NBUCK]
static const size_t OFF_H16   = ALIGN1K(OFF_CNT   + sizeof(int) * NBUCK);     // ushort[NNODES*64]
static const size_t OFF_R16   = ALIGN1K(OFF_H16   + sizeof(unsigned short) * NNODES * FOUT);
static const size_t OFF_STAGE = ALIGN1K(OFF_R16   + sizeof(unsigned short) * NREL * FOUT);
// stage: int[NBUCK*CAP] = 8.0 MB

// Fused: blocks [0, DBLK) bucket edges by dst>>5 with chunk reservation
// (16384 edges/block -> ~42 B runs per bucket, low write amplification);
// blocks [DBLK, ...) compute separable score tables + fp16 copies of h/inputr.
__global__ __launch_bounds__(PTHR) void prep_kernel(
    const float* __restrict__ h, const float* __restrict__ inputr,
    const float* __restrict__ w, const float* __restrict__ a_att,
    const int* __restrict__ A, int* __restrict__ ccnt, int* __restrict__ stage,
    float2* __restrict__ hs2, float2* __restrict__ rr2,
    unsigned short* __restrict__ h16, unsigned short* __restrict__ r16)
{
    const int t = threadIdx.x;
    if (blockIdx.x < DBLK) {
        __shared__ int lcnt[NBUCK];
        __shared__ int gbase[NBUCK];
        for (int i = t; i < NBUCK; i += PTHR) lcnt[i] = 0;
        __syncthreads();

        const int base = blockIdx.x * CHUNK;
        int rec[EPT];
        short bkt[EPT];
        int off[EPT];

        #pragma unroll
        for (int k = 0; k < EPT; k++) {
            const int e = base + k * PTHR + t;
            if (e < NEDGES) {
                const int dn = __builtin_nontemporal_load(A + e);
                const int rn = __builtin_nontemporal_load(A + NEDGES + e);
                const int sn = __builtin_nontemporal_load(A + 2 * NEDGES + e);
                const int b  = dn >> 5;
                rec[k] = ((dn & 31) << 26) | (sn << 10) | rn;
                bkt[k] = (short)b;
                off[k] = atomicAdd(&lcnt[b], 1);
            } else {
                off[k] = -1;
            }
        }
        __syncthreads();

        for (int i = t; i < NBUCK; i += PTHR) {
            const int c = lcnt[i];
            if (c > 0) gbase[i] = i * CAP + atomicAdd(&ccnt[i], c);
        }
        __syncthreads();

        #pragma unroll
        for (int k = 0; k < EPT; k++) {
            if (off[k] >= 0) {
                const int b   = bkt[k];
                const int pos = gbase[b] + off[k];
                if (pos < (b + 1) * CAP)   // safety clamp (cannot trigger)
                    stage[pos] = rec[k];
            }
        }
        return;
    }

    // ---- score tables + fp16 staging: 64 rows per block, 16 lanes each ----
    const int lane = t & 15;
    const int f0   = lane << 2;
    const int g    = (blockIdx.x - DBLK) * 64 + (t >> 4);
    if (g >= NNODES + NREL) return;

    const float4 a00 = *(const float4*)(a_att +   0 + f0);
    const float4 a01 = *(const float4*)(a_att +  64 + f0);
    const float4 a10 = *(const float4*)(a_att + 128 + f0);
    const float4 a11 = *(const float4*)(a_att + 192 + f0);
    const float4 wv  = *(const float4*)(w + f0);

    float p0, p1;
    float4 v;
    if (g < NNODES) {
        v = *(const float4*)(h + (size_t)g * FOUT + f0);
        p0 = v.x * a00.x + v.y * a00.y + v.z * a00.z + v.w * a00.w;
        p1 = v.x * wv.x * a10.x + v.y * wv.y * a10.y
           + v.z * wv.z * a10.z + v.w * wv.w * a10.w;
    } else {
        v = *(const float4*)(inputr + (size_t)(g - NNODES) * FOUT + f0);
        p0 = v.x * a01.x + v.y * a01.y + v.z * a01.z + v.w * a01.w;
        p1 = v.x * a11.x + v.y * a11.y + v.z * a11.z + v.w * a11.w;
    }

    {   // fp16 staging copy (8 B/lane, coalesced 128 B per row)
        ushort4 pk;
        pk.x = __half_as_ushort(__float2half(v.x));
        pk.y = __half_as_ushort(__float2half(v.y));
        pk.z = __half_as_ushort(__float2half(v.z));
        pk.w = __half_as_ushort(__float2half(v.w));
        if (g < NNODES) *(ushort4*)(h16 + (size_t)g * FOUT + f0) = pk;
        else            *(ushort4*)(r16 + (size_t)(g - NNODES) * FOUT + f0) = pk;
    }

    #pragma unroll
    for (int off = 8; off >= 1; off >>= 1) {
        p0 += __shfl_xor(p0, off, 16);
        p1 += __shfl_xor(p1, off, 16);
    }
    if (lane == 0) {
        if (g < NNODES) hs2[g] = make_float2(p0, p1);
        else            rr2[g - NNODES] = make_float2(p0, p1);
    }
}

// One block per bucket: histogram 32 local nodes from stage (pass 1), shuffle
// scan, then scatter into LDS while computing each record's edge weights
// LANE-PARALLEL (one exp covers 64 distinct edges, not 4). Then 4 waves
// aggregate 8 nodes each: quarter-wave per edge, fp16 row gathers, register
// accumulation; inner loop has no transcendentals and no score gathers.
__global__ __launch_bounds__(256) void sortagg_kernel(
    const unsigned short* __restrict__ h16, const unsigned short* __restrict__ r16,
    const float* __restrict__ w,
    const int* __restrict__ stage, const int* __restrict__ ccnt,
    const float2* __restrict__ hs2, const float2* __restrict__ rr2,
    float* __restrict__ out)
{
    __shared__ int    lsort[CAP];
    __shared__ float2 ew[CAP];
    __shared__ int hist[SPAN];
    __shared__ int offs[SPAN];
    __shared__ int sstart[SPAN + 1];

    const int b = blockIdx.x;
    const int t = threadIdx.x;
    int cnt = ccnt[b];
    if (cnt > CAP) cnt = CAP;
    const int base = b * CAP;

    if (t < SPAN) hist[t] = 0;
    __syncthreads();

    for (int i = t; i < cnt; i += 256)
        atomicAdd(&hist[((unsigned)stage[base + i]) >> 26], 1);
    __syncthreads();

    if (t < SPAN) {   // lanes 0..31 of wave 0: inclusive shuffle scan
        const int c = hist[t];
        int v = c;
        #pragma unroll
        for (int d = 1; d < SPAN; d <<= 1) {
            const int u = __shfl_up(v, d);
            if (t >= d) v += u;
        }
        sstart[t] = v - c;
        offs[t]   = v - c;
        if (t == SPAN - 1) sstart[SPAN] = v;
    }
    __syncthreads();

    // Scatter + lane-parallel edge-weight computation (stage region L2-hot).
    for (int i = t; i < cnt; i += 256) {
        const int r = stage[base + i];
        const int pos = atomicAdd(&offs[((unsigned)r) >> 26], 1);
        lsort[pos] = r;
        const int sn = (r >> 10) & 0xFFFF;
        const int rn = r & 1023;
        const float2 hv = hs2[sn];
        const float2 rv = rr2[rn];
        const float sc0 = hv.x + rv.x;
        const float sc1 = hv.y + rv.y;
        ew[pos] = make_float2(__expf(-fmaxf(sc0, NEG_SLOPE * sc0)),
                              __expf(-fmaxf(sc1, NEG_SLOPE * sc1)));
    }
    __syncthreads();

    // ---- aggregation: wave wv handles local nodes wv, wv+4, ..., wv+28 ----
    const int wv = t >> 6;
    const int q  = (t & 63) >> 4;      // quarter: which edge of a group of 4
    const int f4 = (t & 15) << 2;      // feature base (float4)
    const float4 wl = *(const float4*)(w + f4);

    for (int nl = wv; nl < SPAN; nl += 4) {
        const int node = b * SPAN + nl;
        if (node >= NNODES) break;     // only the last bucket; wave-uniform
        const int s0 = sstart[nl];
        const int s1 = sstart[nl + 1];

        float4 acc0 = make_float4(0.f, 0.f, 0.f, 0.f);
        float4 acc1 = make_float4(0.f, 0.f, 0.f, 0.f);
        float sum0 = 0.f, sum1 = 0.f;

        for (int i = s0 + q; i < s1; i += 4) {
            const int p     = lsort[i];        // LDS broadcast
            const float2 ee = ew[i];           // LDS broadcast (b64)
            const int sn = (p >> 10) & 0xFFFF;
            const int rn = p & 1023;

            const uint2 su = *(const uint2*)(h16 + ((size_t)sn << 6) + f4);
            const uint2 ru = *(const uint2*)(r16 + ((size_t)rn << 6) + f4);
            const float2 sxy = __half22float2(__builtin_bit_cast(__half2, su.x));
            const float2 szw = __half22float2(__builtin_bit_cast(__half2, su.y));
            const float2 rxy = __half22float2(__builtin_bit_cast(__half2, ru.x));
            const float2 rzw = __half22float2(__builtin_bit_cast(__half2, ru.y));

            acc0.x += (sxy.x - rxy.x) * ee.x;
            acc0.y += (sxy.y - rxy.y) * ee.x;
            acc0.z += (szw.x - rzw.x) * ee.x;
            acc0.w += (szw.y - rzw.y) * ee.x;
            acc1.x += fmaf(sxy.x, wl.x, -rxy.x) * ee.y;
            acc1.y += fmaf(sxy.y, wl.y, -rxy.y) * ee.y;
            acc1.z += fmaf(szw.x, wl.z, -rzw.x) * ee.y;
            acc1.w += fmaf(szw.y, wl.w, -rzw.y) * ee.y;
            sum0 += ee.x;
            sum1 += ee.y;
        }

        // Combine the 4 quarters: xor-16 then xor-32 swap-adds.
        #pragma unroll
        for (int off = 16; off <= 32; off <<= 1) {
            acc0.x += __shfl_xor(acc0.x, off);
            acc0.y += __shfl_xor(acc0.y, off);
            acc0.z += __shfl_xor(acc0.z, off);
            acc0.w += __shfl_xor(acc0.w, off);
            acc1.x += __shfl_xor(acc1.x, off);
            acc1.y += __shfl_xor(acc1.y, off);
            acc1.z += __shfl_xor(acc1.z, off);
            acc1.w += __shfl_xor(acc1.w, off);
            sum0   += __shfl_xor(sum0, off);
            sum1   += __shfl_xor(sum1, off);
        }

        if (q == 0) {
            const float inv = 1.0f / sum0;
            float4 o = make_float4(acc0.x * inv, acc0.y * inv, acc0.z * inv, acc0.w * inv);
            *(float4*)(out + (size_t)node * FOUT + f4) = o;
        } else if (q == 1) {
            const float inv = 1.0f / sum1;
            float4 o = make_float4(acc1.x * inv, acc1.y * inv, acc1.z * inv, acc1.w * inv);
            *(float4*)(out + ((size_t)NNODES + node) * FOUT + f4) = o;
        }
    }
}

extern "C" void kernel_launch(void* const* d_in, const int* in_sizes, int n_in,
                              void* d_out, int out_size, void* d_ws, size_t ws_size,
                              hipStream_t stream) {
    const float* h      = (const float*)d_in[0];
    const float* inputr = (const float*)d_in[1];
    const int*   A      = (const int*)d_in[2];
    const float* w      = (const float*)d_in[3];
    const float* a_att  = (const float*)d_in[4];

    char* ws = (char*)d_ws;
    float2*         hs2   = (float2*)(ws + OFF_HS);
    float2*         rr2   = (float2*)(ws + OFF_RR);
    int*            ccnt  = (int*)(ws + OFF_CNT);
    unsigned short* h16   = (unsigned short*)(ws + OFF_H16);
    unsigned short* r16   = (unsigned short*)(ws + OFF_R16);
    int*            stage = (int*)(ws + OFF_STAGE);
    float*          out   = (float*)d_out;

    hipMemsetAsync(ccnt, 0, sizeof(int) * NBUCK, stream);

    // 1. Fused: edge bucketing (big chunks) + score tables + fp16 staging.
    prep_kernel<<<dim3(DBLK + PREB), dim3(PTHR), 0, stream>>>(
        h, inputr, w, a_att, A, ccnt, stage, hs2, rr2, h16, r16);
    // 2. Fused per-bucket LDS counting sort + lane-parallel weights + aggregate.
    sortagg_kernel<<<dim3(NBUCK), dim3(256), 0, stream>>>(
        h16, r16, w, stage, ccnt, hs2, rr2, out);
}

// Round 10
// 88.451 us; speedup vs baseline: 1.3941x; 1.0331x over previous
//
#include <hip/hip_runtime.h>
#include <hip/hip_fp16.h>

#define NNODES 50000
#define NREL   1000
#define NEDGES 1600000
#define FOUT   64
#define NEG_SLOPE 0.2f

#define SPAN   16                  // dst nodes per bucket (ln fits in 4 bits); 50000 = 16*3125 exactly
#define NBUCK  3125
#define CAP    704                 // records per bucket (mean 512, sigma ~22.6 -> +8.5 sigma)
#define PTHR   1024                // prep block size
#define EPT    16                  // edges per thread in distribute
#define CHUNK  (PTHR * EPT)        // 16384 edges per distribute block
#define DBLK   98                  // ceil(NEDGES/CHUNK)
#define PREB   797                 // ceil((NNODES+NREL)/64) score blocks (64 rows/block)

// record layout: (ln<<26) | (sn<<10) | rn   -- ln<16, sn<65536, rn<1024

// -------- ws layout (bytes, 1 KiB aligned) --------
#define ALIGN1K(x) (((x) + 1023) & ~((size_t)1023))
static const size_t OFF_HS    = 0;                                            // float2[NNODES]
static const size_t OFF_RR    = ALIGN1K(OFF_HS    + sizeof(float2) * NNODES); // float2[NREL]
static const size_t OFF_CNT   = ALIGN1K(OFF_RR    + sizeof(float2) * NREL);   // int[NBUCK]
static const size_t OFF_H16   = ALIGN1K(OFF_CNT   + sizeof(int) * NBUCK);     // ushort[NNODES*64]
static const size_t OFF_R16   = ALIGN1K(OFF_H16   + sizeof(unsigned short) * NNODES * FOUT);
static const size_t OFF_STAGE = ALIGN1K(OFF_R16   + sizeof(unsigned short) * NREL * FOUT);
// stage: int[NBUCK*CAP] = 8.8 MB

// Fused: blocks [0, DBLK) bucket edges by dst>>4 with chunk reservation;
// blocks [DBLK, ...) compute separable score tables + fp16 copies of h/inputr.
__global__ __launch_bounds__(PTHR) void prep_kernel(
    const float* __restrict__ h, const float* __restrict__ inputr,
    const float* __restrict__ w, const float* __restrict__ a_att,
    const int* __restrict__ A, int* __restrict__ ccnt, int* __restrict__ stage,
    float2* __restrict__ hs2, float2* __restrict__ rr2,
    unsigned short* __restrict__ h16, unsigned short* __restrict__ r16)
{
    const int t = threadIdx.x;
    if (blockIdx.x < DBLK) {
        __shared__ int lcnt[NBUCK];
        __shared__ int gbase[NBUCK];
        for (int i = t; i < NBUCK; i += PTHR) lcnt[i] = 0;
        __syncthreads();

        const int base = blockIdx.x * CHUNK;
        int rec[EPT];
        short bkt[EPT];
        int off[EPT];

        #pragma unroll
        for (int k = 0; k < EPT; k++) {
            const int e = base + k * PTHR + t;
            if (e < NEDGES) {
                const int dn = __builtin_nontemporal_load(A + e);
                const int rn = __builtin_nontemporal_load(A + NEDGES + e);
                const int sn = __builtin_nontemporal_load(A + 2 * NEDGES + e);
                const int b  = dn >> 4;
                rec[k] = ((dn & 15) << 26) | (sn << 10) | rn;
                bkt[k] = (short)b;
                off[k] = atomicAdd(&lcnt[b], 1);
            } else {
                off[k] = -1;
            }
        }
        __syncthreads();

        for (int i = t; i < NBUCK; i += PTHR) {
            const int c = lcnt[i];
            if (c > 0) gbase[i] = i * CAP + atomicAdd(&ccnt[i], c);
        }
        __syncthreads();

        #pragma unroll
        for (int k = 0; k < EPT; k++) {
            if (off[k] >= 0) {
                const int b   = bkt[k];
                const int pos = gbase[b] + off[k];
                if (pos < (b + 1) * CAP)   // safety clamp (cannot trigger)
                    stage[pos] = rec[k];
            }
        }
        return;
    }

    // ---- score tables + fp16 staging: 64 rows per block, 16 lanes each ----
    const int lane = t & 15;
    const int f0   = lane << 2;
    const int g    = (blockIdx.x - DBLK) * 64 + (t >> 4);
    if (g >= NNODES + NREL) return;

    const float4 a00 = *(const float4*)(a_att +   0 + f0);
    const float4 a01 = *(const float4*)(a_att +  64 + f0);
    const float4 a10 = *(const float4*)(a_att + 128 + f0);
    const float4 a11 = *(const float4*)(a_att + 192 + f0);
    const float4 wv  = *(const float4*)(w + f0);

    float p0, p1;
    float4 v;
    if (g < NNODES) {
        v = *(const float4*)(h + (size_t)g * FOUT + f0);
        p0 = v.x * a00.x + v.y * a00.y + v.z * a00.z + v.w * a00.w;
        p1 = v.x * wv.x * a10.x + v.y * wv.y * a10.y
           + v.z * wv.z * a10.z + v.w * wv.w * a10.w;
    } else {
        v = *(const float4*)(inputr + (size_t)(g - NNODES) * FOUT + f0);
        p0 = v.x * a01.x + v.y * a01.y + v.z * a01.z + v.w * a01.w;
        p1 = v.x * a11.x + v.y * a11.y + v.z * a11.z + v.w * a11.w;
    }

    {   // fp16 staging copy (8 B/lane, coalesced 128 B per row)
        ushort4 pk;
        pk.x = __half_as_ushort(__float2half(v.x));
        pk.y = __half_as_ushort(__float2half(v.y));
        pk.z = __half_as_ushort(__float2half(v.z));
        pk.w = __half_as_ushort(__float2half(v.w));
        if (g < NNODES) *(ushort4*)(h16 + (size_t)g * FOUT + f0) = pk;
        else            *(ushort4*)(r16 + (size_t)(g - NNODES) * FOUT + f0) = pk;
    }

    #pragma unroll
    for (int off = 8; off >= 1; off >>= 1) {
        p0 += __shfl_xor(p0, off, 16);
        p1 += __shfl_xor(p1, off, 16);
    }
    if (lane == 0) {
        if (g < NNODES) hs2[g] = make_float2(p0, p1);
        else            rr2[g - NNODES] = make_float2(p0, p1);
    }
}

// One block per bucket (16 nodes): histogram, 16-lane shuffle scan, LDS
// counting sort with LANE-PARALLEL edge weights; then 4 waves aggregate
// 4 nodes each. Wave = 8 octets of 8 lanes: each octet owns one edge,
// each lane owns 8 features (one uint4 fp16 gather).
__global__ __launch_bounds__(256) void sortagg_kernel(
    const unsigned short* __restrict__ h16, const unsigned short* __restrict__ r16,
    const float* __restrict__ w,
    const int* __restrict__ stage, const int* __restrict__ ccnt,
    const float2* __restrict__ hs2, const float2* __restrict__ rr2,
    float* __restrict__ out)
{
    __shared__ int    lsort[CAP];
    __shared__ float2 ew[CAP];
    __shared__ int hist[SPAN];
    __shared__ int offs[SPAN];
    __shared__ int sstart[SPAN + 1];

    const int b = blockIdx.x;
    const int t = threadIdx.x;
    int cnt = ccnt[b];
    if (cnt > CAP) cnt = CAP;
    const int base = b * CAP;

    if (t < SPAN) hist[t] = 0;
    __syncthreads();

    for (int i = t; i < cnt; i += 256)
        atomicAdd(&hist[((unsigned)stage[base + i]) >> 26], 1);
    __syncthreads();

    if (t < SPAN) {   // lanes 0..15 of wave 0: inclusive shuffle scan
        const int c = hist[t];
        int v = c;
        #pragma unroll
        for (int d = 1; d < SPAN; d <<= 1) {
            const int u = __shfl_up(v, d);
            if (t >= d) v += u;
        }
        sstart[t] = v - c;
        offs[t]   = v - c;
        if (t == SPAN - 1) sstart[SPAN] = v;
    }
    __syncthreads();

    // Scatter + lane-parallel edge-weight computation (stage region L2-hot).
    for (int i = t; i < cnt; i += 256) {
        const int r = stage[base + i];
        const int pos = atomicAdd(&offs[((unsigned)r) >> 26], 1);
        lsort[pos] = r;
        const int sn = (r >> 10) & 0xFFFF;
        const int rn = r & 1023;
        const float2 hv = hs2[sn];
        const float2 rv = rr2[rn];
        const float sc0 = hv.x + rv.x;
        const float sc1 = hv.y + rv.y;
        ew[pos] = make_float2(__expf(-fmaxf(sc0, NEG_SLOPE * sc0)),
                              __expf(-fmaxf(sc1, NEG_SLOPE * sc1)));
    }
    __syncthreads();

    // ---- aggregation: wave wv handles local nodes wv, wv+4, wv+8, wv+12 ----
    const int wv  = t >> 6;
    const int oct = (t & 63) >> 3;     // which edge of a group of 8
    const int f8  = (t & 7) << 3;      // feature base (8 features/lane)
    const float4 wl0 = *(const float4*)(w + f8);
    const float4 wl1 = *(const float4*)(w + f8 + 4);

    for (int nl = wv; nl < SPAN; nl += 4) {
        const int node = b * SPAN + nl;          // always < NNODES (exact tiling)
        const int s0 = sstart[nl];
        const int s1 = sstart[nl + 1];

        float4 a0l = make_float4(0.f, 0.f, 0.f, 0.f);
        float4 a0h = make_float4(0.f, 0.f, 0.f, 0.f);
        float4 a1l = make_float4(0.f, 0.f, 0.f, 0.f);
        float4 a1h = make_float4(0.f, 0.f, 0.f, 0.f);
        float sum0 = 0.f, sum1 = 0.f;

        for (int i = s0 + oct; i < s1; i += 8) {
            const int p     = lsort[i];          // LDS broadcast
            const float2 ee = ew[i];             // LDS broadcast (b64)
            const int sn = (p >> 10) & 0xFFFF;
            const int rn = p & 1023;

            const uint4 su = *(const uint4*)(h16 + ((size_t)sn << 6) + f8);
            const uint4 ru = *(const uint4*)(r16 + ((size_t)rn << 6) + f8);
            const float2 s01 = __half22float2(__builtin_bit_cast(__half2, su.x));
            const float2 s23 = __half22float2(__builtin_bit_cast(__half2, su.y));
            const float2 s45 = __half22float2(__builtin_bit_cast(__half2, su.z));
            const float2 s67 = __half22float2(__builtin_bit_cast(__half2, su.w));
            const float2 r01 = __half22float2(__builtin_bit_cast(__half2, ru.x));
            const float2 r23 = __half22float2(__builtin_bit_cast(__half2, ru.y));
            const float2 r45 = __half22float2(__builtin_bit_cast(__half2, ru.z));
            const float2 r67 = __half22float2(__builtin_bit_cast(__half2, ru.w));

            a0l.x += (s01.x - r01.x) * ee.x;
            a0l.y += (s01.y - r01.y) * ee.x;
            a0l.z += (s23.x - r23.x) * ee.x;
            a0l.w += (s23.y - r23.y) * ee.x;
            a0h.x += (s45.x - r45.x) * ee.x;
            a0h.y += (s45.y - r45.y) * ee.x;
            a0h.z += (s67.x - r67.x) * ee.x;
            a0h.w += (s67.y - r67.y) * ee.x;
            a1l.x += fmaf(s01.x, wl0.x, -r01.x) * ee.y;
            a1l.y += fmaf(s01.y, wl0.y, -r01.y) * ee.y;
            a1l.z += fmaf(s23.x, wl0.z, -r23.x) * ee.y;
            a1l.w += fmaf(s23.y, wl0.w, -r23.y) * ee.y;
            a1h.x += fmaf(s45.x, wl1.x, -r45.x) * ee.y;
            a1h.y += fmaf(s45.y, wl1.y, -r45.y) * ee.y;
            a1h.z += fmaf(s67.x, wl1.z, -r67.x) * ee.y;
            a1h.w += fmaf(s67.y, wl1.w, -r67.y) * ee.y;
            sum0 += ee.x;
            sum1 += ee.y;
        }

        // Combine the 8 octets: xor-8 / xor-16 / xor-32 swap-adds.
        #pragma unroll
        for (int off = 8; off <= 32; off <<= 1) {
            a0l.x += __shfl_xor(a0l.x, off);
            a0l.y += __shfl_xor(a0l.y, off);
            a0l.z += __shfl_xor(a0l.z, off);
            a0l.w += __shfl_xor(a0l.w, off);
            a0h.x += __shfl_xor(a0h.x, off);
            a0h.y += __shfl_xor(a0h.y, off);
            a0h.z += __shfl_xor(a0h.z, off);
            a0h.w += __shfl_xor(a0h.w, off);
            a1l.x += __shfl_xor(a1l.x, off);
            a1l.y += __shfl_xor(a1l.y, off);
            a1l.z += __shfl_xor(a1l.z, off);
            a1l.w += __shfl_xor(a1l.w, off);
            a1h.x += __shfl_xor(a1h.x, off);
            a1h.y += __shfl_xor(a1h.y, off);
            a1h.z += __shfl_xor(a1h.z, off);
            a1h.w += __shfl_xor(a1h.w, off);
            sum0   += __shfl_xor(sum0, off);
            sum1   += __shfl_xor(sum1, off);
        }

        if (oct == 0) {
            const float inv = 1.0f / sum0;
            float* o = out + (size_t)node * FOUT + f8;
            *(float4*)(o)     = make_float4(a0l.x * inv, a0l.y * inv, a0l.z * inv, a0l.w * inv);
            *(float4*)(o + 4) = make_float4(a0h.x * inv, a0h.y * inv, a0h.z * inv, a0h.w * inv);
        } else if (oct == 1) {
            const float inv = 1.0f / sum1;
            float* o = out + ((size_t)NNODES + node) * FOUT + f8;
            *(float4*)(o)     = make_float4(a1l.x * inv, a1l.y * inv, a1l.z * inv, a1l.w * inv);
            *(float4*)(o + 4) = make_float4(a1h.x * inv, a1h.y * inv, a1h.z * inv, a1h.w * inv);
        }
    }
}

extern "C" void kernel_launch(void* const* d_in, const int* in_sizes, int n_in,
                              void* d_out, int out_size, void* d_ws, size_t ws_size,
                              hipStream_t stream) {
    const float* h      = (const float*)d_in[0];
    const float* inputr = (const float*)d_in[1];
    const int*   A      = (const int*)d_in[2];
    const float* w      = (const float*)d_in[3];
    const float* a_att  = (const float*)d_in[4];

    char* ws = (char*)d_ws;
    float2*         hs2   = (float2*)(ws + OFF_HS);
    float2*         rr2   = (float2*)(ws + OFF_RR);
    int*            ccnt  = (int*)(ws + OFF_CNT);
    unsigned short* h16   = (unsigned short*)(ws + OFF_H16);
    unsigned short* r16   = (unsigned short*)(ws + OFF_R16);
    int*            stage = (int*)(ws + OFF_STAGE);
    float*          out   = (float*)d_out;

    hipMemsetAsync(ccnt, 0, sizeof(int) * NBUCK, stream);

    // 1. Fused: edge bucketing + score tables + fp16 staging.
    prep_kernel<<<dim3(DBLK + PREB), dim3(PTHR), 0, stream>>>(
        h, inputr, w, a_att, A, ccnt, stage, hs2, rr2, h16, r16);
    // 2. Fused per-bucket LDS counting sort + lane-parallel weights + aggregate.
    sortagg_kernel<<<dim3(NBUCK), dim3(256), 0, stream>>>(
        h16, r16, w, stage, ccnt, hs2, rr2, out);
}